// Round 6
// baseline (70.951 us; speedup 1.0000x reference)
//
#include <hip/hip_runtime.h>

// B=2, S=2048, D_MODEL=1024, H=16, E=64.  Inputs/outputs FLOAT32.
// out = Q (norm * K^T V)  -- reassociated, no S x S scores.
// convert_pack -> qkv_gemm (128x192 tile, ring-3 LDS, fine 2-phase/K-tile
// interleave, counted vmcnt(5), transposed epilogue -> Qt/Kt/Vt) ->
// kv_outer (MFMA) -> qm_out (fused reduce + Q.M).

typedef __attribute__((ext_vector_type(8))) __bf16 bf16x8;
typedef __attribute__((ext_vector_type(8))) short short8;
typedef __attribute__((ext_vector_type(4))) float f32x4;
typedef __attribute__((ext_vector_type(4))) unsigned short ushort4v;

#define NX  4194304   // 4096*1024
#define NW1 1048576   // 1024*1024
#define NW  3145728   // 3*NW1

__device__ __forceinline__ float bf2f(unsigned short u) {
  union { unsigned int i; float f; } v; v.i = ((unsigned int)u) << 16; return v.f;
}
__device__ __forceinline__ unsigned short f2bf(float f) {
  union { float f; unsigned int i; } v; v.f = f;
  unsigned int u = v.i;
  u += 0x7fffu + ((u >> 16) & 1u);   // RNE
  return (unsigned short)(u >> 16);
}

__device__ __forceinline__ void gload_lds16(const void* g, void* l) {
  __builtin_amdgcn_global_load_lds(
      (const __attribute__((address_space(1))) void*)(unsigned long long)(g),
      (__attribute__((address_space(3))) void*)(unsigned int)(unsigned long long)(l),
      16, 0, 0);
}

// ---------------------------------------------------------------------------
// Kernel 0: f32 -> bf16 convert/pack.
// ---------------------------------------------------------------------------
__global__ __launch_bounds__(256) void convert_pack(
    const float* __restrict__ x,
    const float* __restrict__ wq, const float* __restrict__ wk,
    const float* __restrict__ wv,
    const float* __restrict__ bq, const float* __restrict__ bk,
    const float* __restrict__ bv,
    unsigned short* __restrict__ Xbf, unsigned short* __restrict__ Wcat,
    float* __restrict__ Bcat)
{
  const long long t8 = ((long long)blockIdx.x * 256 + threadIdx.x) * 8;
  const float* src;
  unsigned short* dst;
  long long off;
  if (t8 < NX) {
    src = x; dst = Xbf; off = t8;
  } else if (t8 < NX + NW) {
    const long long w = t8 - NX;
    const int z = (int)(w >> 20);
    off = w & (NW1 - 1);
    src = (z == 0) ? wq : (z == 1) ? wk : wv;
    dst = Wcat + (long long)z * NW1;
  } else if (t8 < NX + NW + 3072) {
    const long long bo = t8 - (NX + NW);
    const int z = (int)(bo >> 10);
    const long long o2 = bo & 1023;
    const float* bsrc = (z == 0) ? bq : (z == 1) ? bk : bv;
    *(f32x4*)(Bcat + z * 1024 + o2)     = *(const f32x4*)(bsrc + o2);
    *(f32x4*)(Bcat + z * 1024 + o2 + 4) = *(const f32x4*)(bsrc + o2 + 4);
    return;
  } else {
    return;
  }
  f32x4 v0 = *(const f32x4*)(src + off);
  f32x4 v1 = *(const f32x4*)(src + off + 4);
  union { short8 s; unsigned short u[8]; } o;
#pragma unroll
  for (int j = 0; j < 4; ++j) {
    o.u[j]     = f2bf(v0[j]);
    o.u[4 + j] = f2bf(v1[j]);
  }
  *(short8*)(dst + off) = o.s;
}

// ---------------------------------------------------------------------------
// Kernel 1: C[r,c] = sum_d Xbf[r,d]*Wcat[c,d] + Bcat[c].
// R=4096, C=3072, K=1024.  BM=128 x BN=192, BK=64, 8 waves (2M x 4N),
// grid 32x16 = 512 blocks.  Ring of 3 K-tile buffers (40 KB each, 120 KB).
// Window j (K-tile j): 2 phases (ks=0,1), each:
//   7 ds_read_b128 (frags) + stage part of K-tile j+2 into buf (j+2)%3
//   -> s_barrier -> lgkmcnt(0) -> setprio(1) -> 12 MFMA -> setprio(0)
//   -> [end of window: vmcnt(5)] -> s_barrier
// Ring-3: staged buffer's reads (K-tile j-1) finished a window ago (no WAR
// race); vmcnt(5) keeps exactly one K-tile's stages in flight.
// Epilogue: transposed per-head stores Qt/Kt/Vt[bh][64][2048].
// ---------------------------------------------------------------------------
#define TBUF 40960            // A 128*64*2 (16K) + B 192*64*2 (24K)
__global__ __launch_bounds__(512, 2) void qkv_gemm(
    const unsigned short* __restrict__ Xbf,
    const unsigned short* __restrict__ Wcat,
    const float* __restrict__ Bcat,
    unsigned short* __restrict__ Qt,
    unsigned short* __restrict__ Kt,
    unsigned short* __restrict__ Vt)
{
  __shared__ unsigned char lds[3 * TBUF];   // 120 KB

  const int tid = threadIdx.x;
  int bid = blockIdx.x;
  bid = (bid & 7) * 64 + (bid >> 3);        // bijective XCD swizzle (512%8==0)
  const int colBase = (bid & 15) * 192;     // 16 col tiles
  const int rowBase = (bid >> 4) * 128;     // 32 row tiles

  const int lane = tid & 63;
  const int wid  = tid >> 6;                // 0..7
  const int wm = wid >> 2;                  // 0..1
  const int wn = wid & 3;                   // 0..3
  const int wr = wm * 64;
  const int wc = wn * 48;
  const int lr = lane & 15;
  const int lk = lane >> 4;

  // staging geometry: chunk c = l*512+tid; row = c>>3, seg = tid&7
  const int sr0 = tid >> 3;                 // rows 0..63
  const int sr1 = (512 + tid) >> 3;         // rows 64..127
  const int sr2 = (1024 + tid) >> 3;        // rows 128..191 (B only)
  const int sseg = tid & 7;
  const int dbase = (tid & ~63) * 16;       // wave-uniform LDS dest base

  f32x4 acc[4][3] = {};

  // prologue: kt0 -> buf0, kt1 -> buf1 (5 loads each); kt0 must land.
#pragma unroll
  for (int p = 0; p < 2; ++p) {
    unsigned char* Sb = lds + p * TBUF;
    const int k2 = p * 64;
    gload_lds16(Xbf + (size_t)(rowBase + sr0) * 1024 + k2 + (sseg ^ (sr0 & 7)) * 8,
                Sb + dbase);
    gload_lds16(Xbf + (size_t)(rowBase + sr1) * 1024 + k2 + (sseg ^ (sr1 & 7)) * 8,
                Sb + 8192 + dbase);
    gload_lds16(Wcat + (size_t)(colBase + sr0) * 1024 + k2 + (sseg ^ (sr0 & 7)) * 8,
                Sb + 16384 + dbase);
    gload_lds16(Wcat + (size_t)(colBase + sr1) * 1024 + k2 + (sseg ^ (sr1 & 7)) * 8,
                Sb + 24576 + dbase);
    gload_lds16(Wcat + (size_t)(colBase + sr2) * 1024 + k2 + (sseg ^ (sr2 & 7)) * 8,
                Sb + 32768 + dbase);
  }
  asm volatile("s_waitcnt vmcnt(5)" ::: "memory");
  __builtin_amdgcn_s_barrier();

  for (int j = 0; j < 16; ++j) {
    const unsigned char* Ab = lds + (j % 3) * TBUF;
    const unsigned char* Bb = Ab + 16384;
    const int js = j + 2;
    const bool doStage = (js < 16);
    unsigned char* Sb = lds + (js % 3) * TBUF;
    const int k2 = js * 64;

#pragma unroll
    for (int ks = 0; ks < 2; ++ks) {
      // fragment reads for this phase (current K-tile, k-half ks)
      bf16x8 af[4], bv[3];
#pragma unroll
      for (int m = 0; m < 4; ++m) {
        const int row = wr + m * 16 + lr;
        af[m] = *(const bf16x8*)(Ab + row * 128 +
                                 (((ks * 4 + lk) ^ (row & 7)) * 16));
      }
#pragma unroll
      for (int n = 0; n < 3; ++n) {
        const int row = wc + n * 16 + lr;
        bv[n] = *(const bf16x8*)(Bb + row * 128 +
                                 (((ks * 4 + lk) ^ (row & 7)) * 16));
      }
      // stage part of K-tile j+2 (3 loads in phase 0, 2 in phase 1)
      if (doStage) {
        if (ks == 0) {
          gload_lds16(Xbf + (size_t)(rowBase + sr0) * 1024 + k2 + (sseg ^ (sr0 & 7)) * 8,
                      Sb + dbase);
          gload_lds16(Xbf + (size_t)(rowBase + sr1) * 1024 + k2 + (sseg ^ (sr1 & 7)) * 8,
                      Sb + 8192 + dbase);
          gload_lds16(Wcat + (size_t)(colBase + sr0) * 1024 + k2 + (sseg ^ (sr0 & 7)) * 8,
                      Sb + 16384 + dbase);
        } else {
          gload_lds16(Wcat + (size_t)(colBase + sr1) * 1024 + k2 + (sseg ^ (sr1 & 7)) * 8,
                      Sb + 24576 + dbase);
          gload_lds16(Wcat + (size_t)(colBase + sr2) * 1024 + k2 + (sseg ^ (sr2 & 7)) * 8,
                      Sb + 32768 + dbase);
        }
      }
      __builtin_amdgcn_s_barrier();
      asm volatile("s_waitcnt lgkmcnt(0)" ::: "memory");
      __builtin_amdgcn_s_setprio(1);
#pragma unroll
      for (int m = 0; m < 4; ++m)
#pragma unroll
        for (int n = 0; n < 3; ++n)
          acc[m][n] = __builtin_amdgcn_mfma_f32_16x16x32_bf16(
              af[m], bv[n], acc[m][n], 0, 0, 0);
      __builtin_amdgcn_s_setprio(0);
      if (ks == 1) {
        // window end: keep only the just-issued K-tile's 5 loads in flight
        if (j < 14)       asm volatile("s_waitcnt vmcnt(5)" ::: "memory");
        else if (j == 14) asm volatile("s_waitcnt vmcnt(0)" ::: "memory");
      }
      __builtin_amdgcn_s_barrier();
    }
  }

  // Epilogue.  D mapping: col = lane&15 (lr), row = lk*4 + j.
  const int bB = rowBase >> 11;             // batch
#pragma unroll
  for (int n = 0; n < 3; ++n) {
    const int colG = colBase + wc + n * 16 + lr;
    const float bval = Bcat[colG];
    const int zone = colG >> 10;            // uniform per 16-col fragment
    unsigned short* __restrict__ T = (zone == 0) ? Qt : (zone == 1) ? Kt : Vt;
    const int hf = (colG >> 6) & 15;
    const int f  = colG & 63;
    const size_t rowOff = ((size_t)(bB * 16 + hf) * 64 + f) * 2048;
#pragma unroll
    for (int m = 0; m < 4; ++m) {
      const int t = (rowBase + wr + m * 16 + lk * 4) & 2047;
      ushort4v pk;
#pragma unroll
      for (int jj = 0; jj < 4; ++jj)
        pk[jj] = f2bf(acc[m][n][jj] + bval);
      *(ushort4v*)&T[rowOff + t] = pk;
    }
  }
}

// ---------------------------------------------------------------------------
// Kernel 2 (MFMA): Mpart[blk][f][e] = sum_{t in chunk} Kt[bh][f][t]*Vt[bh][e][t]
// grid 256 blocks x 64 threads (1 wave).  blk = bh*8 + tchunk.
// ---------------------------------------------------------------------------
__global__ __launch_bounds__(64) void kv_outer(
    const unsigned short* __restrict__ Kt,
    const unsigned short* __restrict__ Vt,
    float* __restrict__ Mpart)
{
  const int lane = threadIdx.x;
  const int blk = blockIdx.x;
  const int bh = blk >> 3, tc = blk & 7;
  const int lr = lane & 15, lk = lane >> 4;
  const size_t base = (size_t)bh * 64 * 2048;

  f32x4 acc[4][4] = {};
#pragma unroll
  for (int ks = 0; ks < 8; ++ks) {
    const int t0 = tc * 256 + ks * 32 + lk * 8;
    bf16x8 af[4], bf[4];
#pragma unroll
    for (int m = 0; m < 4; ++m)
      af[m] = *(const bf16x8*)&Kt[base + (size_t)(m * 16 + lr) * 2048 + t0];
#pragma unroll
    for (int n = 0; n < 4; ++n)
      bf[n] = *(const bf16x8*)&Vt[base + (size_t)(n * 16 + lr) * 2048 + t0];
#pragma unroll
    for (int m = 0; m < 4; ++m)
#pragma unroll
      for (int n = 0; n < 4; ++n)
        acc[m][n] = __builtin_amdgcn_mfma_f32_16x16x32_bf16(af[m], bf[n], acc[m][n], 0, 0, 0);
  }
  float* out = Mpart + (size_t)blk * 4096;
#pragma unroll
  for (int m = 0; m < 4; ++m)
#pragma unroll
    for (int n = 0; n < 4; ++n)
#pragma unroll
      for (int j = 0; j < 4; ++j)
        out[(m * 16 + lk * 4 + j) * 64 + n * 16 + lr] = acc[m][n][j];
}

// ---------------------------------------------------------------------------
// Kernel 3: Out[s, h*64+e] = sum_f Qt[bh][f][s] * (norm * sum_ch Mpart)[f][e]
// Fused 8-partial reduce + Q.M.  grid (16 s-chunks, 16 h, 2 b), 256 thr.
// ---------------------------------------------------------------------------
__global__ __launch_bounds__(256) void qm_out(
    const unsigned short* __restrict__ Qt, const float* __restrict__ Mpart,
    float* __restrict__ Out)
{
  __shared__ float Ms[64 * 64];      // 16 KB
  __shared__ float Qst[64 * 132];    // [f][s] padded, ~33 KB
  const int tid = threadIdx.x;
  const int b = blockIdx.z, h = blockIdx.y, s0 = blockIdx.x * 128;
  const int bh = b * 16 + h;

#pragma unroll
  for (int i = 0; i < 4; ++i) {
    const int off = i * 1024 + tid * 4;
    f32x4 s = {};
#pragma unroll
    for (int ch = 0; ch < 8; ++ch)
      s += *(const f32x4*)&Mpart[((size_t)bh * 8 + ch) * 4096 + off];
    s *= 0.125f;   // 64^-0.5
    *(f32x4*)&Ms[off] = s;
  }
  const size_t qbase = (size_t)bh * 64 * 2048;
#pragma unroll
  for (int i = 0; i < 4; ++i) {
    const int slot = i * 256 + tid;          // 0..1023
    const int f = slot >> 4, c = slot & 15;
    short8 q = *(const short8*)&Qt[qbase + (size_t)f * 2048 + s0 + c * 8];
#pragma unroll
    for (int j = 0; j < 8; ++j)
      Qst[f * 132 + c * 8 + j] = bf2f((unsigned short)q[j]);
  }
  __syncthreads();

  const int s = (tid >> 3) * 4;       // 4 rows / thread
  const int e0 = (tid & 7) * 8;       // 8 cols / thread
  float acc2[4][8] = {};
  for (int f = 0; f < 64; ++f) {
    f32x4 m0 = *(const f32x4*)&Ms[f * 64 + e0];
    f32x4 m1 = *(const f32x4*)&Ms[f * 64 + e0 + 4];
#pragma unroll
    for (int i = 0; i < 4; ++i) {
      const float q = Qst[f * 132 + s + i];
#pragma unroll
      for (int j = 0; j < 4; ++j) {
        acc2[i][j]     += q * m0[j];
        acc2[i][j + 4] += q * m1[j];
      }
    }
  }
  const size_t obase = ((size_t)b * 2048 + s0) * 1024 + h * 64;
#pragma unroll
  for (int i = 0; i < 4; ++i) {
    f32x4 o0 = { acc2[i][0], acc2[i][1], acc2[i][2], acc2[i][3] };
    f32x4 o1 = { acc2[i][4], acc2[i][5], acc2[i][6], acc2[i][7] };
    *(f32x4*)&Out[obase + (size_t)(s + i) * 1024 + e0]     = o0;
    *(f32x4*)&Out[obase + (size_t)(s + i) * 1024 + e0 + 4] = o1;
  }
}

extern "C" void kernel_launch(void* const* d_in, const int* in_sizes, int n_in,
                              void* d_out, int out_size, void* d_ws, size_t ws_size,
                              hipStream_t stream) {
  const float* x  = (const float*)d_in[0];
  const float* Wq = (const float*)d_in[1];
  const float* Wk = (const float*)d_in[2];
  const float* Wv = (const float*)d_in[3];
  const float* bq = (const float*)d_in[4];
  const float* bk = (const float*)d_in[5];
  const float* bv = (const float*)d_in[6];
  float* out = (float*)d_out;

  char* ws = (char*)d_ws;
  const size_t MiB = 1024ull * 1024ull;
  unsigned short* Xbf   = (unsigned short*)(ws);              //  8 MiB
  unsigned short* Wcat  = (unsigned short*)(ws + 8  * MiB);   //  6 MiB
  float*          Bcat  = (float*)         (ws + 14 * MiB);   // 12 KiB
  unsigned short* Qt    = (unsigned short*)(ws + 15 * MiB);   //  8 MiB
  unsigned short* Kt    = (unsigned short*)(ws + 23 * MiB);   //  8 MiB
  unsigned short* Vt    = (unsigned short*)(ws + 31 * MiB);   //  8 MiB
  float*          Mpart = (float*)         (ws + 39 * MiB);   //  4 MiB

  convert_pack<<<3586, 256, 0, stream>>>(x, Wq, Wk, Wv, bq, bk, bv,
                                         Xbf, Wcat, Bcat);
  qkv_gemm<<<512, 512, 0, stream>>>(Xbf, Wcat, Bcat, Qt, Kt, Vt);
  kv_outer<<<256, 64, 0, stream>>>(Kt, Vt, Mpart);
  qm_out<<<dim3(16, 16, 2), 256, 0, stream>>>(Qt, Mpart, out);
}

// Round 7
// 66.497 us; speedup vs baseline: 1.0670x; 1.0670x over previous
//
#include <hip/hip_runtime.h>

// B=2, S=2048, D_MODEL=1024, H=16, E=64.  Inputs/outputs FLOAT32.
// out = Q (norm * K^T V)  -- reassociated, no S x S scores.
// convert_pack -> qkv_gemm (256x192, BK=32, ring-4 LDS, 1 barrier + counted
// per-wave vmcnt per K-tile, 3-K-tile prefetch lead, transposed epilogue)
// -> kv_outer (MFMA) -> qm_out (fused reduce + Q.M).

typedef __attribute__((ext_vector_type(8))) __bf16 bf16x8;
typedef __attribute__((ext_vector_type(8))) short short8;
typedef __attribute__((ext_vector_type(4))) float f32x4;
typedef __attribute__((ext_vector_type(4))) unsigned short ushort4v;

#define NX  4194304   // 4096*1024
#define NW1 1048576   // 1024*1024
#define NW  3145728   // 3*NW1

__device__ __forceinline__ float bf2f(unsigned short u) {
  union { unsigned int i; float f; } v; v.i = ((unsigned int)u) << 16; return v.f;
}
__device__ __forceinline__ unsigned short f2bf(float f) {
  union { float f; unsigned int i; } v; v.f = f;
  unsigned int u = v.i;
  u += 0x7fffu + ((u >> 16) & 1u);   // RNE
  return (unsigned short)(u >> 16);
}

__device__ __forceinline__ void gload_lds16(const void* g, void* l) {
  __builtin_amdgcn_global_load_lds(
      (const __attribute__((address_space(1))) void*)(unsigned long long)(g),
      (__attribute__((address_space(3))) void*)(unsigned int)(unsigned long long)(l),
      16, 0, 0);
}

// ---------------------------------------------------------------------------
// Kernel 0: f32 -> bf16 convert/pack.
// ---------------------------------------------------------------------------
__global__ __launch_bounds__(256) void convert_pack(
    const float* __restrict__ x,
    const float* __restrict__ wq, const float* __restrict__ wk,
    const float* __restrict__ wv,
    const float* __restrict__ bq, const float* __restrict__ bk,
    const float* __restrict__ bv,
    unsigned short* __restrict__ Xbf, unsigned short* __restrict__ Wcat,
    float* __restrict__ Bcat)
{
  const long long t8 = ((long long)blockIdx.x * 256 + threadIdx.x) * 8;
  const float* src;
  unsigned short* dst;
  long long off;
  if (t8 < NX) {
    src = x; dst = Xbf; off = t8;
  } else if (t8 < NX + NW) {
    const long long w = t8 - NX;
    const int z = (int)(w >> 20);
    off = w & (NW1 - 1);
    src = (z == 0) ? wq : (z == 1) ? wk : wv;
    dst = Wcat + (long long)z * NW1;
  } else if (t8 < NX + NW + 3072) {
    const long long bo = t8 - (NX + NW);
    const int z = (int)(bo >> 10);
    const long long o2 = bo & 1023;
    const float* bsrc = (z == 0) ? bq : (z == 1) ? bk : bv;
    *(f32x4*)(Bcat + z * 1024 + o2)     = *(const f32x4*)(bsrc + o2);
    *(f32x4*)(Bcat + z * 1024 + o2 + 4) = *(const f32x4*)(bsrc + o2 + 4);
    return;
  } else {
    return;
  }
  f32x4 v0 = *(const f32x4*)(src + off);
  f32x4 v1 = *(const f32x4*)(src + off + 4);
  union { short8 s; unsigned short u[8]; } o;
#pragma unroll
  for (int j = 0; j < 4; ++j) {
    o.u[j]     = f2bf(v0[j]);
    o.u[4 + j] = f2bf(v1[j]);
  }
  *(short8*)(dst + off) = o.s;
}

// ---------------------------------------------------------------------------
// Kernel 1: C[r,c] = sum_d Xbf[r,d]*Wcat[c,d] + Bcat[c].
// R=4096, C=3072, K=1024.  BM=256 x BN=192, BK=32, 8 waves (2M x 4N),
// grid 16x16 = 256 (1 block/CU).  Ring-4 LDS (4 x 28 KB).
// Per K-tile j: counted per-wave vmcnt (A-waves 8, B-waves 6) -> barrier ->
// 11 ds_read_b128 -> stage K-tile j+3 (A-waves 4 loads, B-waves 3) ->
// 24 MFMA (setprio-wrapped).  One barrier + one checkpoint per K-tile;
// waited-on loads have a 3-K-tile lead; vmcnt never 0 until the tail.
// Epilogue: transposed per-head stores Qt/Kt/Vt[bh][64][2048], 8B packed.
// ---------------------------------------------------------------------------
#define ABUF_B 16384          // 256*32*2
#define BBUF_B 12288          // 192*32*2
#define TILE_B 28672
__global__ __launch_bounds__(512, 2) void qkv_gemm(
    const unsigned short* __restrict__ Xbf,
    const unsigned short* __restrict__ Wcat,
    const float* __restrict__ Bcat,
    unsigned short* __restrict__ Qt,
    unsigned short* __restrict__ Kt,
    unsigned short* __restrict__ Vt)
{
  __shared__ unsigned char lds[4 * TILE_B];   // 112 KB

  const int tid = threadIdx.x;
  int bid = blockIdx.x;
  bid = (bid & 7) * 32 + (bid >> 3);          // bijective XCD swizzle
  const int colBase = (bid & 15) * 192;       // 16 col tiles
  const int rowBase = (bid >> 4) * 256;       // 16 row tiles

  const int lane = tid & 63;
  const int wid  = tid >> 6;                  // 0..7
  const int wr = (wid >> 2) * 128;            // 2 M-waves
  const int wc = (wid & 3) * 48;              // 4 N-waves
  const int lr = lane & 15;
  const int lk = lane >> 4;
  const int fofs = (lk ^ ((lr >> 1) & 3)) << 4;   // swizzled frag byte offset

  const bool isA = (tid < 256);
  const int tloc = isA ? tid : (tid - 256);

  // staging: A tile = 1024 16B units (4/thread), B tile = 768 (3/thread)
  const unsigned short* gptr[4];
  int lofs[4];
#pragma unroll
  for (int l = 0; l < 4; ++l) {
    const int unit = l * 256 + tloc;
    const int row  = unit >> 2;
    const int sc   = ((unit & 3) ^ ((row >> 1) & 3)) << 3;  // elems
    const int rowc = (!isA && row > 191) ? 0 : row;         // l=3 unused for B
    gptr[l] = isA ? (Xbf  + (size_t)(rowBase + rowc) * 1024 + sc)
                  : (Wcat + (size_t)(colBase + rowc) * 1024 + sc);
    lofs[l] = (isA ? 0 : ABUF_B) + unit * 16;
  }

  f32x4 acc[8][3] = {};

#define STAGE(j3)                                                    \
  { unsigned char* Sb_ = lds + ((j3) & 3) * TILE_B;                  \
    const int ko_ = (j3) * 32;                                       \
    if (isA) {                                                       \
      _Pragma("unroll") for (int l = 0; l < 4; ++l)                  \
        gload_lds16(gptr[l] + ko_, Sb_ + lofs[l]);                   \
    } else {                                                         \
      _Pragma("unroll") for (int l = 0; l < 3; ++l)                  \
        gload_lds16(gptr[l] + ko_, Sb_ + lofs[l]);                   \
    } }

#define KSTEP(j, DOSTAGE, VMA, VMB)                                       \
  { if (isA) asm volatile("s_waitcnt vmcnt(" #VMA ")" ::: "memory");      \
    else     asm volatile("s_waitcnt vmcnt(" #VMB ")" ::: "memory");      \
    asm volatile("s_barrier" ::: "memory");                               \
    const unsigned char* Ab_ = lds + ((j) & 3) * TILE_B;                  \
    const unsigned char* Bb_ = Ab_ + ABUF_B;                              \
    bf16x8 a_[8], b_[3];                                                  \
    _Pragma("unroll") for (int m = 0; m < 8; ++m)                         \
      a_[m] = *(const bf16x8*)(Ab_ + (wr + m * 16 + lr) * 64 + fofs);     \
    _Pragma("unroll") for (int n = 0; n < 3; ++n)                         \
      b_[n] = *(const bf16x8*)(Bb_ + (wc + n * 16 + lr) * 64 + fofs);     \
    if (DOSTAGE) STAGE((j) + 3);                                          \
    __builtin_amdgcn_s_setprio(1);                                        \
    _Pragma("unroll") for (int m = 0; m < 8; ++m)                         \
      _Pragma("unroll") for (int n = 0; n < 3; ++n)                       \
        acc[m][n] = __builtin_amdgcn_mfma_f32_16x16x32_bf16(              \
            a_[m], b_[n], acc[m][n], 0, 0, 0);                            \
    __builtin_amdgcn_s_setprio(0);                                        \
  }

  // prologue: stage K-tiles 0,1,2 (A-waves 12 loads, B-waves 9)
  STAGE(0); STAGE(1); STAGE(2);

  for (int j = 0; j < 29; ++j) KSTEP(j, true, 8, 6);
  KSTEP(29, false, 8, 6);
  KSTEP(30, false, 4, 3);
  KSTEP(31, false, 0, 0);
#undef KSTEP
#undef STAGE

  // Epilogue.  D mapping: col = lane&15 (lr), row = lk*4 + jj.
  const int bB = rowBase >> 11;               // batch
#pragma unroll
  for (int n = 0; n < 3; ++n) {
    const int colG = colBase + wc + n * 16 + lr;
    const float bval = Bcat[colG];
    const int zone = colG >> 10;              // uniform per 16-col fragment
    unsigned short* __restrict__ T = (zone == 0) ? Qt : (zone == 1) ? Kt : Vt;
    const int hf = (colG >> 6) & 15;
    const int f  = colG & 63;
    const size_t rowOff = ((size_t)(bB * 16 + hf) * 64 + f) * 2048;
#pragma unroll
    for (int m = 0; m < 8; ++m) {
      const int t = (rowBase + wr + m * 16 + lk * 4) & 2047;
      ushort4v pk;
#pragma unroll
      for (int jj = 0; jj < 4; ++jj)
        pk[jj] = f2bf(acc[m][n][jj] + bval);
      *(ushort4v*)&T[rowOff + t] = pk;
    }
  }
}

// ---------------------------------------------------------------------------
// Kernel 2 (MFMA): Mpart[blk][f][e] = sum_{t in chunk} Kt[bh][f][t]*Vt[bh][e][t]
// grid 256 blocks x 64 threads (1 wave).  blk = bh*8 + tchunk.
// ---------------------------------------------------------------------------
__global__ __launch_bounds__(64) void kv_outer(
    const unsigned short* __restrict__ Kt,
    const unsigned short* __restrict__ Vt,
    float* __restrict__ Mpart)
{
  const int lane = threadIdx.x;
  const int blk = blockIdx.x;
  const int bh = blk >> 3, tc = blk & 7;
  const int lr = lane & 15, lk = lane >> 4;
  const size_t base = (size_t)bh * 64 * 2048;

  f32x4 acc[4][4] = {};
#pragma unroll
  for (int ks = 0; ks < 8; ++ks) {
    const int t0 = tc * 256 + ks * 32 + lk * 8;
    bf16x8 af[4], bf[4];
#pragma unroll
    for (int m = 0; m < 4; ++m)
      af[m] = *(const bf16x8*)&Kt[base + (size_t)(m * 16 + lr) * 2048 + t0];
#pragma unroll
    for (int n = 0; n < 4; ++n)
      bf[n] = *(const bf16x8*)&Vt[base + (size_t)(n * 16 + lr) * 2048 + t0];
#pragma unroll
    for (int m = 0; m < 4; ++m)
#pragma unroll
      for (int n = 0; n < 4; ++n)
        acc[m][n] = __builtin_amdgcn_mfma_f32_16x16x32_bf16(af[m], bf[n], acc[m][n], 0, 0, 0);
  }
  float* out = Mpart + (size_t)blk * 4096;
#pragma unroll
  for (int m = 0; m < 4; ++m)
#pragma unroll
    for (int n = 0; n < 4; ++n)
#pragma unroll
      for (int j = 0; j < 4; ++j)
        out[(m * 16 + lk * 4 + j) * 64 + n * 16 + lr] = acc[m][n][j];
}

// ---------------------------------------------------------------------------
// Kernel 3: Out[s, h*64+e] = sum_f Qt[bh][f][s] * (norm * sum_ch Mpart)[f][e]
// Fused 8-partial reduce + Q.M.  grid (16 s-chunks, 16 h, 2 b), 256 thr.
// ---------------------------------------------------------------------------
__global__ __launch_bounds__(256) void qm_out(
    const unsigned short* __restrict__ Qt, const float* __restrict__ Mpart,
    float* __restrict__ Out)
{
  __shared__ float Ms[64 * 64];      // 16 KB
  __shared__ float Qst[64 * 132];    // [f][s] padded
  const int tid = threadIdx.x;
  const int b = blockIdx.z, h = blockIdx.y, s0 = blockIdx.x * 128;
  const int bh = b * 16 + h;

#pragma unroll
  for (int i = 0; i < 4; ++i) {
    const int off = i * 1024 + tid * 4;
    f32x4 s = {};
#pragma unroll
    for (int ch = 0; ch < 8; ++ch)
      s += *(const f32x4*)&Mpart[((size_t)bh * 8 + ch) * 4096 + off];
    s *= 0.125f;   // 64^-0.5
    *(f32x4*)&Ms[off] = s;
  }
  const size_t qbase = (size_t)bh * 64 * 2048;
#pragma unroll
  for (int i = 0; i < 4; ++i) {
    const int slot = i * 256 + tid;          // 0..1023
    const int f = slot >> 4, c = slot & 15;
    short8 q = *(const short8*)&Qt[qbase + (size_t)f * 2048 + s0 + c * 8];
#pragma unroll
    for (int j = 0; j < 8; ++j)
      Qst[f * 132 + c * 8 + j] = bf2f((unsigned short)q[j]);
  }
  __syncthreads();

  const int s = (tid >> 3) * 4;       // 4 rows / thread
  const int e0 = (tid & 7) * 8;       // 8 cols / thread
  float acc2[4][8] = {};
  for (int f = 0; f < 64; ++f) {
    f32x4 m0 = *(const f32x4*)&Ms[f * 64 + e0];
    f32x4 m1 = *(const f32x4*)&Ms[f * 64 + e0 + 4];
#pragma unroll
    for (int i = 0; i < 4; ++i) {
      const float q = Qst[f * 132 + s + i];
#pragma unroll
      for (int j = 0; j < 4; ++j) {
        acc2[i][j]     += q * m0[j];
        acc2[i][j + 4] += q * m1[j];
      }
    }
  }
  const size_t obase = ((size_t)b * 2048 + s0) * 1024 + h * 64;
#pragma unroll
  for (int i = 0; i < 4; ++i) {
    f32x4 o0 = { acc2[i][0], acc2[i][1], acc2[i][2], acc2[i][3] };
    f32x4 o1 = { acc2[i][4], acc2[i][5], acc2[i][6], acc2[i][7] };
    *(f32x4*)&Out[obase + (size_t)(s + i) * 1024 + e0]     = o0;
    *(f32x4*)&Out[obase + (size_t)(s + i) * 1024 + e0 + 4] = o1;
  }
}

extern "C" void kernel_launch(void* const* d_in, const int* in_sizes, int n_in,
                              void* d_out, int out_size, void* d_ws, size_t ws_size,
                              hipStream_t stream) {
  const float* x  = (const float*)d_in[0];
  const float* Wq = (const float*)d_in[1];
  const float* Wk = (const float*)d_in[2];
  const float* Wv = (const float*)d_in[3];
  const float* bq = (const float*)d_in[4];
  const float* bk = (const float*)d_in[5];
  const float* bv = (const float*)d_in[6];
  float* out = (float*)d_out;

  char* ws = (char*)d_ws;
  const size_t MiB = 1024ull * 1024ull;
  unsigned short* Xbf   = (unsigned short*)(ws);              //  8 MiB
  unsigned short* Wcat  = (unsigned short*)(ws + 8  * MiB);   //  6 MiB
  float*          Bcat  = (float*)         (ws + 14 * MiB);   // 12 KiB
  unsigned short* Qt    = (unsigned short*)(ws + 15 * MiB);   //  8 MiB
  unsigned short* Kt    = (unsigned short*)(ws + 23 * MiB);   //  8 MiB
  unsigned short* Vt    = (unsigned short*)(ws + 31 * MiB);   //  8 MiB
  float*          Mpart = (float*)         (ws + 39 * MiB);   //  4 MiB

  convert_pack<<<3586, 256, 0, stream>>>(x, Wq, Wk, Wv, bq, bk, bv,
                                         Xbf, Wcat, Bcat);
  qkv_gemm<<<256, 512, 0, stream>>>(Xbf, Wcat, Bcat, Qt, Kt, Vt);
  kv_outer<<<256, 64, 0, stream>>>(Kt, Vt, Mpart);
  qm_out<<<dim3(16, 16, 2), 256, 0, stream>>>(Qt, Mpart, out);
}